// Round 13
// baseline (123.060 us; speedup 1.0000x reference)
//
#include <hip/hip_runtime.h>

// rmsdLoss via associative affine scan — R23.
// R22 post-mortem: fused 1-wave version cut instrs (-18%) but REGRESSED
// (96.7 -> 101.1): tlP+tlT = 96 persistent VGPRs -> ~200 peak -> 2 waves/SIMD
// (8/CU) vs R20's 16 -> latency re-exposed. Algebra verified (passed).
// R23 keeps the fusion but ELIMINATES tl storage: since D = G_P^T G_T is a
// rotation (|Dv|=|v|), sum|u-Dv-d|^2 = suu + svv + n|d|^2 + 2 d.(D sv)
// - 2<D,C>_F - 2 su.d  with C = sum u v^T (9), su,sv (6), suu,svv (2) —
// 17 accumulators built ON THE FLY in an INTERLEAVED compose (step k of P
// and T together; u=P.t, v=T.t accumulated immediately, guarded).
// Instructions ~net-neutral vs R22 (~2900/row, diff-loop -> in-loop accum);
// registers: peak ~100-110 (2x12 chain state + 17 accum + 34-float load
// batch of 4 steps x both chains) -> <=128 -> 4 waves/SIMD (16/CU) via
// waves_per_eu(4,4). R22's savings at R20's occupancy. LDS = 0, 1 barrier = 0.
// Predicted: dur_us -> ~91-94 (kernel ~15-17us). If >=96: occupancy theory
// wrong or spills (WRITE_SIZE) -> relax pin.

#define LROW  4087
#define NSTEP 1021
#define NROW  2048
#define CHUNK 16
#define EPSF  1e-6f
#define INVMEAN (1.0f / (2048.0f * 1024.0f * 3.0f))

__device__ __forceinline__ float frcp(float x){ return __builtin_amdgcn_rcpf(x); }
__device__ __forceinline__ float frsq(float x){ return __builtin_amdgcn_rsqf(x); }

struct Ch { float c0x,c0y,c0z, c1x,c1y,c1z, c2x,c2y,c2z, tx,ty,tz; };

// One chain step: closed-form rotation update + translation (R19 algebra).
// b1,b2 arrive pre-clipped+denormed. first folds at compile time (unrolled).
template<bool CLIP>
__device__ __forceinline__ void stepK(Ch& X, float s0, float s1, float dr,
                                      const float b1, const float b2,
                                      const bool first){
  if (CLIP){
    s0 = fminf(fmaxf(s0, -1.f), 1.f);
    s1 = fminf(fmaxf(s1, -1.f), 1.f);
    dr = fminf(fmaxf(dr, -1.f), 1.f);
  }
  const float d = fmaf(dr, 1.75f, 3.25f);
  float ct = (b1*b1 + b2*b2 - d*d) * frcp(2.0f*b1*b2);
  ct = fminf(fmaxf(ct, -1.0f + EPSF), 1.0f - EPSF);
  const float omc = fmaxf(1.0f - ct*ct, 1e-12f);
  const float ist = frsq(omc);           // 1/st
  const float st  = omc * ist;           // sqrt(omc)
  const float r2 = s0*s0 + s1*s1;
  const bool ok = r2 > 1e-36f;
  const float ir = ok ? frsq(r2) : 0.0f;
  const float scv = s0 * ir;                 // sin(chi)
  const float ccv = ok ? s1 * ir : 1.0f;     // cos(chi)
  const float hx = -ct, hy = st*ccv, hz = st*scv;   // unit step dir
  if (first){
    X.c0x=hx;    X.c0y=hy;      X.c0z=hz;
    X.c1x=-st;   X.c1y=hx*ccv;  X.c1z=hx*scv;
    X.c2x=0.f;   X.c2y=-scv;    X.c2z=ccv;
    X.tx=b2*hx;  X.ty=b2*hy;    X.tz=b2*hz;
  } else {
    const float n0x = X.c0x*hx + X.c1x*hy + X.c2x*hz;
    const float n0y = X.c0y*hx + X.c1y*hy + X.c2y*hz;
    const float n0z = X.c0z*hx + X.c1z*hy + X.c2z*hz;
    X.tx = fmaf(b2, n0x, X.tx);
    X.ty = fmaf(b2, n0y, X.ty);
    X.tz = fmaf(b2, n0z, X.tz);
    const float n1x = ist * fmaf(hx, n0x, -X.c0x);
    const float n1y = ist * fmaf(hx, n0y, -X.c0y);
    const float n1z = ist * fmaf(hx, n0z, -X.c0z);
    const float n2x = fmaf(ccv, X.c2x, -scv*X.c1x);
    const float n2y = fmaf(ccv, X.c2y, -scv*X.c1y);
    const float n2z = fmaf(ccv, X.c2z, -scv*X.c1z);
    X.c0x=n0x; X.c0y=n0y; X.c0z=n0z;
    X.c1x=n1x; X.c1y=n1y; X.c1z=n1z;
    X.c2x=n2x; X.c2y=n2y; X.c2z=n2z;
  }
}

// Fold (F0, a2): G = F0 * E ; G.t = a2 + F0 * E.t   (R19/R22 verified)
__device__ __forceinline__ void foldG(
    const float rb0, const float rd0, const float rb1,
    const float e0x, const float e0y, const float e0z,
    const float e1x, const float e1y, const float e1z,
    const float tx, const float ty, const float tz,
    float &g0x, float &g0y, float &g0z,
    float &g1x, float &g1y, float &g1z,
    float &g2x, float &g2y, float &g2z,
    float &gtx, float &gty, float &gtz,
    float &a1x, float &a2x, float &a2y)
{
  const float bl0 = fmaf(rb0, 1.05f, 1.95f);
  const float d0  = fmaf(rd0, 1.75f, 3.25f);
  const float b1f = fmaf(rb1, 1.05f, 1.95f);
  float ct0 = (bl0*bl0 + b1f*b1f - d0*d0) * frcp(2.0f*bl0*b1f);
  ct0 = fminf(fmaxf(ct0, -1.0f + EPSF), 1.0f - EPSF);
  const float st0 = sqrtf(fmaxf(1.0f - ct0*ct0, 0.0f));
  a1x = bl0;
  a2x = bl0 - b1f*ct0;
  a2y = b1f*st0;
  const float e2x = e0y*e1z - e0z*e1y;
  const float e2y = e0z*e1x - e0x*e1z;
  const float e2z = e0x*e1y - e0y*e1x;
  g0x = -ct0*e0x - st0*e0y; g0y = st0*e0x - ct0*e0y; g0z = e0z;
  g1x = -ct0*e1x - st0*e1y; g1y = st0*e1x - ct0*e1y; g1z = e1z;
  g2x = -ct0*e2x - st0*e2y; g2y = st0*e2x - ct0*e2y; g2z = e2z;
  gtx = a2x - ct0*tx - st0*ty;
  gty = a2y + st0*tx - ct0*ty;
  gtz = tz;
}

__global__ void __launch_bounds__(64) __attribute__((amdgpu_waves_per_eu(4, 4)))
rmsd_kernel(const float* __restrict__ pred, const float* __restrict__ targ,
            float* __restrict__ ws){
  const int row = blockIdx.x;
  const int ln  = threadIdx.x;        // 0..63, one wave
  const int j0  = ln * CHUNK;         // first step owned (<= 1008)

  const float* __restrict__ vp = pred + (size_t)row * LROW;
  const float* __restrict__ vt = targ + (size_t)row * LROW;

  // ---- interleaved compose with on-the-fly moment accumulation ----
  Ch P, T;
  float C00=0,C01=0,C02=0, C10=0,C11=0,C12=0, C20=0,C21=0,C22=0;
  float sux=0,suy=0,suz=0, svx=0,svy=0,svz=0, suu=0, svv=0;

  #pragma unroll
  for (int h = 0; h < 4; ++h){                 // 4 batches x 4 steps
    const int base = j0 + (h << 2);
    float pS0[4], pS1[4], pDD[4], pBV[5];
    float tS0[4], tS1[4], tDD[4], tBV[5];
    #pragma unroll
    for (int k = 0; k < 4; ++k){
      pS0[k] = vp[2*(base+k)];   pS1[k] = vp[2*(base+k)+1];
      tS0[k] = vt[2*(base+k)];   tS1[k] = vt[2*(base+k)+1];
      pDD[k] = vp[2043 + base + k];             // lane63 tail: valid mem, guarded out
      tDD[k] = vt[2043 + base + k];
    }
    #pragma unroll
    for (int m = 0; m < 5; ++m){
      int ix = 3065 + base + m;
      if (ix > 4086) ix = 4086;                 // tail clamp (garbage bounded)
      float bp = vp[ix];
      bp = fminf(fmaxf(bp, -1.f), 1.f);         // pred clipped
      pBV[m] = fmaf(bp, 1.05f, 1.95f);
      tBV[m] = fmaf(vt[ix], 1.05f, 1.95f);      // targ unclipped
    }
    #pragma unroll
    for (int k = 0; k < 4; ++k){
      const bool first = (h == 0) && (k == 0);
      stepK<true >(P, pS0[k], pS1[k], pDD[k], pBV[k], pBV[k+1], first);
      stepK<false>(T, tS0[k], tS1[k], tDD[k], tBV[k], tBV[k+1], first);
      if (base + k < NSTEP){
        const float ux=P.tx, uy=P.ty, uz=P.tz;
        const float vx=T.tx, vy=T.ty, vz=T.tz;
        C00=fmaf(ux,vx,C00); C01=fmaf(ux,vy,C01); C02=fmaf(ux,vz,C02);
        C10=fmaf(uy,vx,C10); C11=fmaf(uy,vy,C11); C12=fmaf(uy,vz,C12);
        C20=fmaf(uz,vx,C20); C21=fmaf(uz,vy,C21); C22=fmaf(uz,vz,C22);
        sux+=ux; suy+=uy; suz+=uz;
        svx+=vx; svy+=vy; svz+=vz;
        suu=fmaf(ux,ux,suu); suu=fmaf(uy,uy,suu); suu=fmaf(uz,uz,suu);
        svv=fmaf(vx,vx,svv); svv=fmaf(vy,vy,svv); svv=fmaf(vz,vz,svv);
      }
    }
  }

  // ---- fused in-wave inclusive ROTATION scans (P and T, 6-float each) ----
  float p0x=P.c0x,p0y=P.c0y,p0z=P.c0z, p1x=P.c1x,p1y=P.c1y,p1z=P.c1z;
  float q0x=T.c0x,q0y=T.c0y,q0z=T.c0z, q1x=T.c1x,q1y=T.c1y,q1z=T.c1z;
  #pragma unroll
  for (int off = 1; off < 64; off <<= 1){
    const float A0x=__shfl_up(p0x,off), A0y=__shfl_up(p0y,off), A0z=__shfl_up(p0z,off);
    const float A1x=__shfl_up(p1x,off), A1y=__shfl_up(p1y,off), A1z=__shfl_up(p1z,off);
    const float B0x=__shfl_up(q0x,off), B0y=__shfl_up(q0y,off), B0z=__shfl_up(q0z,off);
    const float B1x=__shfl_up(q1x,off), B1y=__shfl_up(q1y,off), B1z=__shfl_up(q1z,off);
    const float A2x = A0y*A1z - A0z*A1y;
    const float A2y = A0z*A1x - A0x*A1z;
    const float A2z = A0x*A1y - A0y*A1x;
    const float B2x = B0y*B1z - B0z*B1y;
    const float B2y = B0z*B1x - B0x*B1z;
    const float B2z = B0x*B1y - B0y*B1x;
    const float np0x = A0x*p0x + A1x*p0y + A2x*p0z;
    const float np0y = A0y*p0x + A1y*p0y + A2y*p0z;
    const float np0z = A0z*p0x + A1z*p0y + A2z*p0z;
    const float np1x = A0x*p1x + A1x*p1y + A2x*p1z;
    const float np1y = A0y*p1x + A1y*p1y + A2y*p1z;
    const float np1z = A0z*p1x + A1z*p1y + A2z*p1z;
    const float nq0x = B0x*q0x + B1x*q0y + B2x*q0z;
    const float nq0y = B0y*q0x + B1y*q0y + B2y*q0z;
    const float nq0z = B0z*q0x + B1z*q0y + B2z*q0z;
    const float nq1x = B0x*q1x + B1x*q1y + B2x*q1z;
    const float nq1y = B0y*q1x + B1y*q1y + B2y*q1z;
    const float nq1z = B0z*q1x + B1z*q1y + B2z*q1z;
    if (ln >= off){
      p0x=np0x; p0y=np0y; p0z=np0z; p1x=np1x; p1y=np1y; p1z=np1z;
      q0x=nq0x; q0y=nq0y; q0z=nq0z; q1x=nq1x; q1y=nq1y; q1z=nq1z;
    }
  }

  // exclusive rotation prefixes
  float e0x=__shfl_up(p0x,1), e0y=__shfl_up(p0y,1), e0z=__shfl_up(p0z,1);
  float e1x=__shfl_up(p1x,1), e1y=__shfl_up(p1y,1), e1z=__shfl_up(p1z,1);
  float f0x=__shfl_up(q0x,1), f0y=__shfl_up(q0y,1), f0z=__shfl_up(q0z,1);
  float f1x=__shfl_up(q1x,1), f1y=__shfl_up(q1y,1), f1z=__shfl_up(q1z,1);
  if (ln == 0){
    e0x=1.f; e0y=0.f; e0z=0.f; e1x=0.f; e1y=1.f; e1z=0.f;
    f0x=1.f; f0y=0.f; f0z=0.f; f1x=0.f; f1y=1.f; f1z=0.f;
  }

  // ---- fused translation scans: w = E * t_chunk, commutative sum scan ----
  float tPx, tPy, tPz, tTx, tTy, tTz;
  {
    const float e2x = e0y*e1z - e0z*e1y;
    const float e2y = e0z*e1x - e0x*e1z;
    const float e2z = e0x*e1y - e0y*e1x;
    const float f2x = f0y*f1z - f0z*f1y;
    const float f2y = f0z*f1x - f0x*f1z;
    const float f2z = f0x*f1y - f0y*f1x;
    const float wPx = e0x*P.tx + e1x*P.ty + e2x*P.tz;
    const float wPy = e0y*P.tx + e1y*P.ty + e2y*P.tz;
    const float wPz = e0z*P.tx + e1z*P.ty + e2z*P.tz;
    const float wTx = f0x*T.tx + f1x*T.ty + f2x*T.tz;
    const float wTy = f0y*T.tx + f1y*T.ty + f2y*T.tz;
    const float wTz = f0z*T.tx + f1z*T.ty + f2z*T.tz;
    float sPx=wPx, sPy=wPy, sPz=wPz, sTx=wTx, sTy=wTy, sTz=wTz;
    #pragma unroll
    for (int off = 1; off < 64; off <<= 1){
      const float aPx=__shfl_up(sPx,off), aPy=__shfl_up(sPy,off), aPz=__shfl_up(sPz,off);
      const float aTx=__shfl_up(sTx,off), aTy=__shfl_up(sTy,off), aTz=__shfl_up(sTz,off);
      if (ln >= off){ sPx+=aPx; sPy+=aPy; sPz+=aPz; sTx+=aTx; sTy+=aTy; sTz+=aTz; }
    }
    tPx = sPx - wPx; tPy = sPy - wPy; tPz = sPz - wPz;   // exclusive prefixes
    tTx = sTx - wTx; tTy = sTy - wTy; tTz = sTz - wTz;
  }

  // ---- folds -> per-lane G_P, G_T ----
  float P0x,P0y,P0z, P1x,P1y,P1z, P2x,P2y,P2z, Ptx,Pty,Ptz, Pa1,Pa2x,Pa2y;
  float T0x,T0y,T0z, T1x,T1y,T1z, T2x,T2y,T2z, Ttx,Tty,Ttz, Ta1,Ta2x,Ta2y;
  {
    float rb0 = fminf(fmaxf(vp[3064], -1.f), 1.f);
    float rd0 = fminf(fmaxf(vp[2042], -1.f), 1.f);
    float rb1 = fminf(fmaxf(vp[3065], -1.f), 1.f);
    foldG(rb0, rd0, rb1, e0x,e0y,e0z, e1x,e1y,e1z, tPx,tPy,tPz,
          P0x,P0y,P0z, P1x,P1y,P1z, P2x,P2y,P2z, Ptx,Pty,Ptz, Pa1,Pa2x,Pa2y);
    foldG(vt[3064], vt[2042], vt[3065], f0x,f0y,f0z, f1x,f1y,f1z, tTx,tTy,tTz,
          T0x,T0y,T0z, T1x,T1y,T1z, T2x,T2y,T2z, Ttx,Tty,Ttz, Ta1,Ta2x,Ta2y);
  }

  // ---- D = G_P^T G_T (row-major), d = G_P^T (gt_T - gt_P) ----
  const float D00 = P0x*T0x + P0y*T0y + P0z*T0z;
  const float D10 = P1x*T0x + P1y*T0y + P1z*T0z;
  const float D20 = P2x*T0x + P2y*T0y + P2z*T0z;
  const float D01 = P0x*T1x + P0y*T1y + P0z*T1z;
  const float D11 = P1x*T1x + P1y*T1y + P1z*T1z;
  const float D21 = P2x*T1x + P2y*T1y + P2z*T1z;
  const float D02 = P0x*T2x + P0y*T2y + P0z*T2z;
  const float D12 = P1x*T2x + P1y*T2y + P1z*T2z;
  const float D22 = P2x*T2x + P2y*T2y + P2z*T2z;
  const float bx = Ttx - Ptx, by = Tty - Pty, bz = Ttz - Ptz;
  const float dtx = P0x*bx + P0y*by + P0z*bz;
  const float dty = P1x*bx + P1y*by + P1z*bz;
  const float dtz = P2x*bx + P2y*by + P2z*bz;

  // ---- closed-form lane loss (no tl storage):
  // sum|u - Dv - d|^2 = suu + svv + n|d|^2 + 2 d.(D sv) - 2<D,C> - 2 su.d ----
  const int n = (NSTEP - j0) < CHUNK ? (NSTEP - j0) : CHUNK;   // 16 (lane63: 13)
  const float Dsvx = D00*svx + D01*svy + D02*svz;
  const float Dsvy = D10*svx + D11*svy + D12*svz;
  const float Dsvz = D20*svx + D21*svy + D22*svz;
  const float DC = D00*C00 + D01*C01 + D02*C02
                 + D10*C10 + D11*C11 + D12*C12
                 + D20*C20 + D21*C21 + D22*C22;
  const float dd2 = dtx*dtx + dty*dty + dtz*dtz;
  const float dDsv = dtx*Dsvx + dty*Dsvy + dtz*Dsvz;
  const float sud  = sux*dtx + suy*dty + suz*dtz;
  float acc = suu + svv + (float)n*dd2 + 2.0f*dDsv - 2.0f*DC - 2.0f*sud;

  if (ln == 0){
    const float dx = Pa1  - Ta1;    // a1 differs only in x; a0 diff = 0
    const float dy = Pa2x - Ta2x;   // a2 differs in x,y (z = 0)
    const float dz = Pa2y - Ta2y;
    acc += dx*dx + dy*dy + dz*dz;
  }
  #pragma unroll
  for (int off = 32; off > 0; off >>= 1) acc += __shfl_down(acc, off);
  // plain store, zero contention (atomic drain was the 43us floor, R17)
  if (ln == 0) ws[row] = acc;
}

// 1 block: reduce 2048 per-row partials -> out. 8 coalesced loads/thread.
__global__ void __launch_bounds__(256, 1)
reduce_kernel(const float* __restrict__ ws, float* __restrict__ out){
  __shared__ float wsum[4];
  const int tid = threadIdx.x;
  float a = 0.0f;
  #pragma unroll
  for (int i = 0; i < 8; ++i) a += ws[tid + (i << 8)];
  #pragma unroll
  for (int off = 32; off > 0; off >>= 1) a += __shfl_down(a, off);
  if ((tid & 63) == 0) wsum[tid >> 6] = a;
  __syncthreads();
  if (tid == 0) out[0] = (wsum[0] + wsum[1] + wsum[2] + wsum[3]) * INVMEAN;
}

extern "C" void kernel_launch(void* const* d_in, const int* in_sizes, int n_in,
                              void* d_out, int out_size, void* d_ws, size_t ws_size,
                              hipStream_t stream) {
  const float* pred = (const float*)d_in[0];
  const float* targ = (const float*)d_in[1];
  float* out = (float*)d_out;
  float* ws  = (float*)d_ws;   // needs 2048 floats = 8 KB

  rmsd_kernel<<<NROW, 64, 0, stream>>>(pred, targ, ws);
  reduce_kernel<<<1, 256, 0, stream>>>(ws, out);
}